// Round 5
// baseline (264.804 us; speedup 1.0000x reference)
//
#include <hip/hip_runtime.h>

// Problem constants (fixed by setup_inputs: bs=8, N=M=4096, C=128)
#define BS 8
#define NN 4096
#define MM 4096
#define CC 128
#define XT 128            // x rows per block
#define MT 128            // cols per m-tile
#define MH 1024           // cols per block
#define NMT (MH / MT)     // 8 m-tiles per block
#define NXT (NN / XT)     // 32 x-tiles

#define FINF_BITS 0x7F800000u

typedef __attribute__((ext_vector_type(8))) short bf16x8;
typedef __attribute__((ext_vector_type(4))) float f32x4;

// RNE fp32 -> bf16 (inputs are finite normals)
__device__ inline ushort f2bf(float f) {
    unsigned u = __float_as_uint(f);
    unsigned r = (u + 0x7FFFu + ((u >> 16) & 1u)) >> 16;
    return (ushort)r;
}

// ---------------------------------------------------------------------------
// prep: fp32->bf16 copies + exact fp32 row norms + rowmin/colmin=+inf + out=0
// ---------------------------------------------------------------------------
__global__ void ch_prep(const float* __restrict__ x, const float* __restrict__ y,
                        ushort* __restrict__ x16, ushort* __restrict__ y16,
                        float* __restrict__ xn, float* __restrict__ yn,
                        unsigned* __restrict__ rowmin, unsigned* __restrict__ colmin,
                        float* __restrict__ out) {
    int gid = blockIdx.x * blockDim.x + threadIdx.x;
    size_t i = (size_t)gid * 4;

    float4 v = *(const float4*)(x + i);
    ushort4 o;
    o.x = f2bf(v.x); o.y = f2bf(v.y); o.z = f2bf(v.z); o.w = f2bf(v.w);
    *(ushort4*)(x16 + i) = o;
    float sx = v.x * v.x + v.y * v.y + v.z * v.z + v.w * v.w;

    float4 w = *(const float4*)(y + i);
    ushort4 p;
    p.x = f2bf(w.x); p.y = f2bf(w.y); p.z = f2bf(w.z); p.w = f2bf(w.w);
    *(ushort4*)(y16 + i) = p;
    float sy = w.x * w.x + w.y * w.y + w.z * w.z + w.w * w.w;

#pragma unroll
    for (int mask = 1; mask <= 16; mask <<= 1) {
        sx += __shfl_xor(sx, mask, 64);
        sy += __shfl_xor(sy, mask, 64);
    }
    if ((threadIdx.x & 31) == 0) {
        int row = gid >> 5;
        xn[row] = sx;
        yn[row] = sy;
    }
    if (gid < BS * NN) {
        rowmin[gid] = FINF_BITS;
        colmin[gid] = FINF_BITS;
    }
    if (gid == 0) out[0] = 0.0f;
}

// ---------------------------------------------------------------------------
// main kernel: persistent m-loop over 8 m-tiles. x-tile (128x128 bf16) staged
// ONCE into XOR-swizzled LDS (2-way banks = free); y fragments direct from
// global (L2-resident). One barrier per block, none in the m-loop.
// 4 waves = 2x2 quadrants of a 128x128 tile; 64 MFMAs/wave per m-tile.
// Row d^2 mins in registers across all tiles; col mins via LDS atomicMin,
// flushed with global atomicMin at block end. sqrt deferred to finalize.
// launch_bounds(256,4): 4 blocks/CU (grid 1024 = one full pass), regs <= 128.
// ---------------------------------------------------------------------------
__global__ __launch_bounds__(256, 4) void ch_tile(
    const ushort* __restrict__ X, const ushort* __restrict__ Y,
    const float* __restrict__ xn, const float* __restrict__ yn,
    unsigned* __restrict__ rowmin, unsigned* __restrict__ colmin) {

    __shared__ ushort xs[XT * CC];     // 32 KB, chunk-swizzled
    __shared__ unsigned coltile[MH];   // 4 KB

    const int b  = blockIdx.z;
    const int xt = blockIdx.x;         // 0..31
    const int mh = blockIdx.y;         // 0..3
    const int n0 = xt * XT;
    const int m0 = mh * MH;
    const int tid  = threadIdx.x;
    const int wave = tid >> 6;
    const int lane = tid & 63;
    const int lc   = lane & 15;        // A/B row, C col
    const int quad = lane >> 4;        // k-chunk, C row group
    const int wm = wave >> 1;
    const int wn = wave & 1;

    // ---- stage x tile into swizzled LDS (16B chunk c at slot c^(row&7)) ----
    const ushort* Xb = X + ((size_t)b * NN + n0) * CC;
#pragma unroll
    for (int s = 0; s < 8; ++s) {
        int flat = s * 256 + tid;      // 2048 chunks = 128 rows x 16
        int r = flat >> 4, c = flat & 15;
        int cs = c ^ (r & 7);
        *(bf16x8*)(xs + r * CC + cs * 8) = *(const bf16x8*)(Xb + (size_t)r * CC + c * 8);
    }
    for (int c2 = tid; c2 < MH; c2 += 256) coltile[c2] = FINF_BITS;
    __syncthreads();

    float rm[4][4];
#pragma unroll
    for (int i = 0; i < 4; ++i)
#pragma unroll
        for (int r = 0; r < 4; ++r) rm[i][r] = __builtin_inff();

    const ushort* Yb  = Y + ((size_t)b * MM + m0) * CC;
    const float*  ynb = yn + (size_t)b * MM + m0;
    const float*  xnb = xn + (size_t)b * NN + n0;
    const int xrow = (wm * 64 + lc) * CC;
    const int xsw  = lc & 7;

#pragma unroll 1
    for (int mt = 0; mt < NMT; ++mt) {
        const ushort* Ymt = Yb + (size_t)(mt * MT + wn * 64 + lc) * CC + quad * 8;

        f32x4 acc[4][4];
        const f32x4 z = {0.f, 0.f, 0.f, 0.f};
#pragma unroll
        for (int kt = 0; kt < 4; ++kt) {
            bf16x8 af[4], yf[4];
            const int cs = ((kt * 4 + quad) ^ xsw) * 8;
#pragma unroll
            for (int i = 0; i < 4; ++i)
                af[i] = *(const bf16x8*)(xs + xrow + i * 16 * CC + cs);
#pragma unroll
            for (int j = 0; j < 4; ++j)
                yf[j] = *(const bf16x8*)(Ymt + (size_t)j * 16 * CC + kt * 32);
#pragma unroll
            for (int j = 0; j < 4; ++j)
#pragma unroll
                for (int i = 0; i < 4; ++i)
                    acc[i][j] = __builtin_amdgcn_mfma_f32_16x16x32_bf16(
                        af[i], yf[j], (kt == 0) ? z : acc[i][j], 0, 0, 0);
        }

        // ---- epilogue: d^2 mins (sqrt/clamp deferred) ----
        float ynr[4];
#pragma unroll
        for (int j = 0; j < 4; ++j)
            ynr[j] = ynb[mt * MT + wn * 64 + j * 16 + lc];
        float xnr[4][4];
#pragma unroll
        for (int i = 0; i < 4; ++i) {
            float4 t = *(const float4*)(xnb + wm * 64 + i * 16 + quad * 4);
            xnr[i][0] = t.x; xnr[i][1] = t.y; xnr[i][2] = t.z; xnr[i][3] = t.w;
        }

        float cmv[4];
#pragma unroll
        for (int j = 0; j < 4; ++j) cmv[j] = __builtin_inff();

#pragma unroll
        for (int i = 0; i < 4; ++i)
#pragma unroll
            for (int j = 0; j < 4; ++j) {
                f32x4 a = acc[i][j];
#pragma unroll
                for (int r = 0; r < 4; ++r) {
                    float d2 = xnr[i][r] + fmaf(-2.0f, a[r], ynr[j]);
                    rm[i][r] = fminf(rm[i][r], d2);
                    cmv[j]   = fminf(cmv[j], d2);
                }
            }

        // col reduce across quads, then LDS atomic
#pragma unroll
        for (int mask = 16; mask <= 32; mask <<= 1)
#pragma unroll
            for (int j = 0; j < 4; ++j)
                cmv[j] = fminf(cmv[j], __shfl_xor(cmv[j], mask, 64));
        if (quad == 0) {
#pragma unroll
            for (int j = 0; j < 4; ++j)
                atomicMin(&coltile[mt * MT + wn * 64 + j * 16 + lc],
                          __float_as_uint(fmaxf(cmv[j], 0.0f)));
        }
    }

    // ---- row mins: reduce across the 16 lc lanes, one global atomic each ----
#pragma unroll
    for (int mask = 1; mask <= 8; mask <<= 1)
#pragma unroll
        for (int i = 0; i < 4; ++i)
#pragma unroll
            for (int r = 0; r < 4; ++r)
                rm[i][r] = fminf(rm[i][r], __shfl_xor(rm[i][r], mask, 64));
    if (lc == 0) {
#pragma unroll
        for (int i = 0; i < 4; ++i)
#pragma unroll
            for (int r = 0; r < 4; ++r)
                atomicMin(&rowmin[(size_t)b * NN + n0 + wm * 64 + i * 16 + quad * 4 + r],
                          __float_as_uint(fmaxf(rm[i][r], 0.0f)));
    }

    // ---- col mins: flush LDS tile with global atomics ----
    __syncthreads();
    for (int c2 = tid; c2 < MH; c2 += 256)
        atomicMin(&colmin[(size_t)b * MM + m0 + c2], coltile[c2]);
}

// ---------------------------------------------------------------------------
// finalize: total = (sum w1*sqrt(rowmin) + sum w2*sqrt(colmin)) / 2
// ---------------------------------------------------------------------------
__global__ void ch_finalize(const unsigned* __restrict__ rowmin,
                            const unsigned* __restrict__ colmin,
                            const float* __restrict__ w1,
                            const float* __restrict__ w2,
                            float* __restrict__ out) {
    int i = blockIdx.x * blockDim.x + threadIdx.x;
    int stride = gridDim.x * blockDim.x;
    float s = 0.f;
    for (int idx = i; idx < BS * NN; idx += stride)
        s += w1[idx] * sqrtf(__uint_as_float(rowmin[idx])) +
             w2[idx] * sqrtf(__uint_as_float(colmin[idx]));
#pragma unroll
    for (int off = 32; off > 0; off >>= 1) s += __shfl_down(s, off, 64);
    __shared__ float ls[4];
    int lane = threadIdx.x & 63, wv = threadIdx.x >> 6;
    if (lane == 0) ls[wv] = s;
    __syncthreads();
    if (threadIdx.x == 0) {
        float t = ls[0] + ls[1] + ls[2] + ls[3];
        atomicAdd(out, 0.5f * t);
    }
}

extern "C" void kernel_launch(void* const* d_in, const int* in_sizes, int n_in,
                              void* d_out, int out_size, void* d_ws, size_t ws_size,
                              hipStream_t stream) {
    const float* set1 = (const float*)d_in[0];
    const float* set2 = (const float*)d_in[1];
    const float* w1   = (const float*)d_in[2];
    const float* w2   = (const float*)d_in[3];
    float* out = (float*)d_out;

    // workspace layout (~16.5 MiB)
    ushort*   x16    = (ushort*)d_ws;                        // 8 MB
    ushort*   y16    = x16 + (size_t)BS * NN * CC;           // 8 MB
    float*    xn     = (float*)(y16 + (size_t)BS * MM * CC); // 128 KB
    float*    yn     = xn + BS * NN;                         // 128 KB
    unsigned* rowmin = (unsigned*)(yn + BS * MM);            // 128 KB (d^2 bits)
    unsigned* colmin = rowmin + BS * NN;                     // 128 KB (d^2 bits)

    ch_prep<<<BS * NN * CC / 4 / 256, 256, 0, stream>>>(
        set1, set2, x16, y16, xn, yn, rowmin, colmin, out);

    dim3 grid(NXT, MM / MH, BS);
    ch_tile<<<grid, 256, 0, stream>>>(x16, y16, xn, yn, rowmin, colmin);

    ch_finalize<<<64, 256, 0, stream>>>(rowmin, colmin, w1, w2, out);
}

// Round 6
// 206.026 us; speedup vs baseline: 1.2853x; 1.2853x over previous
//
#include <hip/hip_runtime.h>

// Problem constants (fixed by setup_inputs: bs=8, N=M=4096, C=128)
#define BS 8
#define NN 4096
#define MM 4096
#define CC 128
#define XT 128            // x rows per block
#define MT 128            // cols per m-tile
#define MH 512            // cols per block
#define NMT (MH / MT)     // 4 m-tiles per block
#define NXT (NN / XT)     // 32 x-tiles

#define FINF_BITS 0x7F800000u

typedef __attribute__((ext_vector_type(8))) short bf16x8;
typedef __attribute__((ext_vector_type(4))) float f32x4;

// RNE fp32 -> bf16 (inputs are finite normals)
__device__ inline ushort f2bf(float f) {
    unsigned u = __float_as_uint(f);
    unsigned r = (u + 0x7FFFu + ((u >> 16) & 1u)) >> 16;
    return (ushort)r;
}

// ---------------------------------------------------------------------------
// prep: fp32->bf16 copies + exact fp32 row norms + rowmin/colmin=+inf + out=0
// ---------------------------------------------------------------------------
__global__ void ch_prep(const float* __restrict__ x, const float* __restrict__ y,
                        ushort* __restrict__ x16, ushort* __restrict__ y16,
                        float* __restrict__ xn, float* __restrict__ yn,
                        unsigned* __restrict__ rowmin, unsigned* __restrict__ colmin,
                        float* __restrict__ out) {
    int gid = blockIdx.x * blockDim.x + threadIdx.x;
    size_t i = (size_t)gid * 4;

    float4 v = *(const float4*)(x + i);
    ushort4 o;
    o.x = f2bf(v.x); o.y = f2bf(v.y); o.z = f2bf(v.z); o.w = f2bf(v.w);
    *(ushort4*)(x16 + i) = o;
    float sx = v.x * v.x + v.y * v.y + v.z * v.z + v.w * v.w;

    float4 w = *(const float4*)(y + i);
    ushort4 p;
    p.x = f2bf(w.x); p.y = f2bf(w.y); p.z = f2bf(w.z); p.w = f2bf(w.w);
    *(ushort4*)(y16 + i) = p;
    float sy = w.x * w.x + w.y * w.y + w.z * w.z + w.w * w.w;

#pragma unroll
    for (int mask = 1; mask <= 16; mask <<= 1) {
        sx += __shfl_xor(sx, mask, 64);
        sy += __shfl_xor(sy, mask, 64);
    }
    if ((threadIdx.x & 31) == 0) {
        int row = gid >> 5;
        xn[row] = sx;
        yn[row] = sy;
    }
    if (gid < BS * NN) {
        rowmin[gid] = FINF_BITS;
        colmin[gid] = FINF_BITS;
    }
    if (gid == 0) out[0] = 0.0f;
}

// ---------------------------------------------------------------------------
// main kernel: m-loop over 4 m-tiles. x-tile (128x128 bf16) staged once into
// XOR-swizzled LDS; y fragments direct from global (L2-resident). One barrier
// per block. 4 waves = 2x2 quadrants of 128x128; 64 MFMAs/wave per m-tile.
// Row d^2 mins in registers; col mins via LDS atomicMin -> global atomicMin.
// sqrt deferred. launch_bounds(256,3): 170-reg budget — fits the ~140-165
// live set WITHOUT spill (R5's (256,4)=128 cap spilled 300 MB to scratch).
// ---------------------------------------------------------------------------
__global__ __launch_bounds__(256, 3) void ch_tile(
    const ushort* __restrict__ X, const ushort* __restrict__ Y,
    const float* __restrict__ xn, const float* __restrict__ yn,
    unsigned* __restrict__ rowmin, unsigned* __restrict__ colmin) {

    __shared__ ushort xs[XT * CC];     // 32 KB, chunk-swizzled
    __shared__ unsigned coltile[MH];   // 2 KB

    const int b  = blockIdx.z;
    const int xt = blockIdx.x;         // 0..31
    const int mh = blockIdx.y;         // 0..7
    const int n0 = xt * XT;
    const int m0 = mh * MH;
    const int tid  = threadIdx.x;
    const int wave = tid >> 6;
    const int lane = tid & 63;
    const int lc   = lane & 15;        // A/B row, C col
    const int quad = lane >> 4;        // k-chunk, C row group
    const int wm = wave >> 1;
    const int wn = wave & 1;

    // ---- stage x tile into swizzled LDS (16B chunk c at slot c^(row&7)) ----
    const ushort* Xb = X + ((size_t)b * NN + n0) * CC;
#pragma unroll
    for (int s = 0; s < 8; ++s) {
        int flat = s * 256 + tid;      // 2048 chunks = 128 rows x 16
        int r = flat >> 4, c = flat & 15;
        int cs = c ^ (r & 7);
        *(bf16x8*)(xs + r * CC + cs * 8) = *(const bf16x8*)(Xb + (size_t)r * CC + c * 8);
    }
    for (int c2 = tid; c2 < MH; c2 += 256) coltile[c2] = FINF_BITS;
    __syncthreads();

    float rm[4][4];
#pragma unroll
    for (int i = 0; i < 4; ++i)
#pragma unroll
        for (int r = 0; r < 4; ++r) rm[i][r] = __builtin_inff();

    const ushort* Yb  = Y + ((size_t)b * MM + m0) * CC;
    const float*  ynb = yn + (size_t)b * MM + m0;
    const float*  xnb = xn + (size_t)b * NN + n0;
    const int xrow = (wm * 64 + lc) * CC;
    const int xsw  = lc & 7;

#pragma unroll 1
    for (int mt = 0; mt < NMT; ++mt) {
        const ushort* Ymt = Yb + (size_t)(mt * MT + wn * 64 + lc) * CC + quad * 8;

        // hoist the y-norm loads ahead of the MFMA chain
        float ynr[4];
#pragma unroll
        for (int j = 0; j < 4; ++j)
            ynr[j] = ynb[mt * MT + wn * 64 + j * 16 + lc];

        f32x4 acc[4][4];
        const f32x4 z = {0.f, 0.f, 0.f, 0.f};
#pragma unroll
        for (int kt = 0; kt < 4; ++kt) {
            bf16x8 af[4], yf[4];
            const int cs = ((kt * 4 + quad) ^ xsw) * 8;
#pragma unroll
            for (int j = 0; j < 4; ++j)
                yf[j] = *(const bf16x8*)(Ymt + (size_t)j * 16 * CC + kt * 32);
#pragma unroll
            for (int i = 0; i < 4; ++i)
                af[i] = *(const bf16x8*)(xs + xrow + i * 16 * CC + cs);
#pragma unroll
            for (int j = 0; j < 4; ++j)
#pragma unroll
                for (int i = 0; i < 4; ++i)
                    acc[i][j] = __builtin_amdgcn_mfma_f32_16x16x32_bf16(
                        af[i], yf[j], (kt == 0) ? z : acc[i][j], 0, 0, 0);
        }

        // ---- epilogue: d^2 mins (sqrt/clamp deferred) ----
        float xnr[4][4];
#pragma unroll
        for (int i = 0; i < 4; ++i) {
            float4 t = *(const float4*)(xnb + wm * 64 + i * 16 + quad * 4);
            xnr[i][0] = t.x; xnr[i][1] = t.y; xnr[i][2] = t.z; xnr[i][3] = t.w;
        }

        float cmv[4];
#pragma unroll
        for (int j = 0; j < 4; ++j) cmv[j] = __builtin_inff();

#pragma unroll
        for (int i = 0; i < 4; ++i)
#pragma unroll
            for (int j = 0; j < 4; ++j) {
                f32x4 a = acc[i][j];
#pragma unroll
                for (int r = 0; r < 4; ++r) {
                    float d2 = xnr[i][r] + fmaf(-2.0f, a[r], ynr[j]);
                    rm[i][r] = fminf(rm[i][r], d2);
                    cmv[j]   = fminf(cmv[j], d2);
                }
            }

        // col reduce across quads, then LDS atomic
#pragma unroll
        for (int mask = 16; mask <= 32; mask <<= 1)
#pragma unroll
            for (int j = 0; j < 4; ++j)
                cmv[j] = fminf(cmv[j], __shfl_xor(cmv[j], mask, 64));
        if (quad == 0) {
#pragma unroll
            for (int j = 0; j < 4; ++j)
                atomicMin(&coltile[mt * MT + wn * 64 + j * 16 + lc],
                          __float_as_uint(fmaxf(cmv[j], 0.0f)));
        }
    }

    // ---- row mins: reduce across the 16 lc lanes, one global atomic each ----
#pragma unroll
    for (int mask = 1; mask <= 8; mask <<= 1)
#pragma unroll
        for (int i = 0; i < 4; ++i)
#pragma unroll
            for (int r = 0; r < 4; ++r)
                rm[i][r] = fminf(rm[i][r], __shfl_xor(rm[i][r], mask, 64));
    if (lc == 0) {
#pragma unroll
        for (int i = 0; i < 4; ++i)
#pragma unroll
            for (int r = 0; r < 4; ++r)
                atomicMin(&rowmin[(size_t)b * NN + n0 + wm * 64 + i * 16 + quad * 4 + r],
                          __float_as_uint(fmaxf(rm[i][r], 0.0f)));
    }

    // ---- col mins: flush LDS tile with global atomics ----
    __syncthreads();
    for (int c2 = tid; c2 < MH; c2 += 256)
        atomicMin(&colmin[(size_t)b * MM + m0 + c2], coltile[c2]);
}

// ---------------------------------------------------------------------------
// finalize: total = (sum w1*sqrt(rowmin) + sum w2*sqrt(colmin)) / 2
// ---------------------------------------------------------------------------
__global__ void ch_finalize(const unsigned* __restrict__ rowmin,
                            const unsigned* __restrict__ colmin,
                            const float* __restrict__ w1,
                            const float* __restrict__ w2,
                            float* __restrict__ out) {
    int i = blockIdx.x * blockDim.x + threadIdx.x;
    int stride = gridDim.x * blockDim.x;
    float s = 0.f;
    for (int idx = i; idx < BS * NN; idx += stride)
        s += w1[idx] * sqrtf(__uint_as_float(rowmin[idx])) +
             w2[idx] * sqrtf(__uint_as_float(colmin[idx]));
#pragma unroll
    for (int off = 32; off > 0; off >>= 1) s += __shfl_down(s, off, 64);
    __shared__ float ls[4];
    int lane = threadIdx.x & 63, wv = threadIdx.x >> 6;
    if (lane == 0) ls[wv] = s;
    __syncthreads();
    if (threadIdx.x == 0) {
        float t = ls[0] + ls[1] + ls[2] + ls[3];
        atomicAdd(out, 0.5f * t);
    }
}

extern "C" void kernel_launch(void* const* d_in, const int* in_sizes, int n_in,
                              void* d_out, int out_size, void* d_ws, size_t ws_size,
                              hipStream_t stream) {
    const float* set1 = (const float*)d_in[0];
    const float* set2 = (const float*)d_in[1];
    const float* w1   = (const float*)d_in[2];
    const float* w2   = (const float*)d_in[3];
    float* out = (float*)d_out;

    // workspace layout (~16.5 MiB)
    ushort*   x16    = (ushort*)d_ws;                        // 8 MB
    ushort*   y16    = x16 + (size_t)BS * NN * CC;           // 8 MB
    float*    xn     = (float*)(y16 + (size_t)BS * MM * CC); // 128 KB
    float*    yn     = xn + BS * NN;                         // 128 KB
    unsigned* rowmin = (unsigned*)(yn + BS * MM);            // 128 KB (d^2 bits)
    unsigned* colmin = rowmin + BS * NN;                     // 128 KB (d^2 bits)

    ch_prep<<<BS * NN * CC / 4 / 256, 256, 0, stream>>>(
        set1, set2, x16, y16, xn, yn, rowmin, colmin, out);

    dim3 grid(NXT, MM / MH, BS);
    ch_tile<<<grid, 256, 0, stream>>>(x16, y16, xn, yn, rowmin, colmin);

    ch_finalize<<<64, 256, 0, stream>>>(rowmin, colmin, w1, w2, out);
}

// Round 7
// 168.541 us; speedup vs baseline: 1.5712x; 1.2224x over previous
//
#include <hip/hip_runtime.h>

// Problem constants (fixed by setup_inputs: bs=8, N=M=4096, C=128)
#define BS 8
#define NN 4096
#define MM 4096
#define CC 128
#define XT 128            // x rows per block
#define MT 128            // cols per m-tile
#define MH 512            // cols per block
#define NMT (MH / MT)     // 4 m-tiles per block
#define NXT (NN / XT)     // 32 x-tiles

#define FINF_BITS 0x7F800000u

typedef __attribute__((ext_vector_type(8))) short bf16x8;
typedef __attribute__((ext_vector_type(4))) float f32x4;

// RNE fp32 -> bf16 (inputs are finite normals)
__device__ inline ushort f2bf(float f) {
    unsigned u = __float_as_uint(f);
    unsigned r = (u + 0x7FFFu + ((u >> 16) & 1u)) >> 16;
    return (ushort)r;
}

// ---------------------------------------------------------------------------
// prep: fp32->bf16 copies + exact fp32 row norms + rowmin/colmin=+inf + out=0
// ---------------------------------------------------------------------------
__global__ void ch_prep(const float* __restrict__ x, const float* __restrict__ y,
                        ushort* __restrict__ x16, ushort* __restrict__ y16,
                        float* __restrict__ xn, float* __restrict__ yn,
                        unsigned* __restrict__ rowmin, unsigned* __restrict__ colmin,
                        float* __restrict__ out) {
    int gid = blockIdx.x * blockDim.x + threadIdx.x;
    size_t i = (size_t)gid * 4;

    float4 v = *(const float4*)(x + i);
    ushort4 o;
    o.x = f2bf(v.x); o.y = f2bf(v.y); o.z = f2bf(v.z); o.w = f2bf(v.w);
    *(ushort4*)(x16 + i) = o;
    float sx = v.x * v.x + v.y * v.y + v.z * v.z + v.w * v.w;

    float4 w = *(const float4*)(y + i);
    ushort4 p;
    p.x = f2bf(w.x); p.y = f2bf(w.y); p.z = f2bf(w.z); p.w = f2bf(w.w);
    *(ushort4*)(y16 + i) = p;
    float sy = w.x * w.x + w.y * w.y + w.z * w.z + w.w * w.w;

#pragma unroll
    for (int mask = 1; mask <= 16; mask <<= 1) {
        sx += __shfl_xor(sx, mask, 64);
        sy += __shfl_xor(sy, mask, 64);
    }
    if ((threadIdx.x & 31) == 0) {
        int row = gid >> 5;
        xn[row] = sx;
        yn[row] = sy;
    }
    if (gid < BS * NN) {
        rowmin[gid] = FINF_BITS;
        colmin[gid] = FINF_BITS;
    }
    if (gid == 0) out[0] = 0.0f;
}

// ---------------------------------------------------------------------------
// main kernel (R4 structure + register diet):
//  - x fragments register-resident for the block (64 VGPR), y fragments
//    direct from global (L2-resident). No LDS tiles, no barriers in m-loop.
//  - 4 waves = 2x2 quadrants of a 128x128 tile; 64 MFMAs/wave per m-tile.
//  - Epilogue per m-tile, processed one i-chunk at a time to keep transient
//    register pressure low: row d^2-mins shuffle-reduced over lc then LDS
//    atomicMin into rowtile; col mins shuffle-reduced over quad then LDS
//    atomicMin into coltile. Flushed once with global atomicMin at block end.
//  - NO restrictive launch_bounds: R5/R6 showed forcing min-waves makes the
//    allocator spill long-lived state to scratch (121-306 MB). Instead the
//    xnr/rm diet (-32 persistent regs vs R4) aims natural unified usage
//    below the 170-reg 3-waves/SIMD threshold.
// ---------------------------------------------------------------------------
__global__ __launch_bounds__(256) void ch_tile(
    const ushort* __restrict__ X, const ushort* __restrict__ Y,
    const float* __restrict__ xn, const float* __restrict__ yn,
    unsigned* __restrict__ rowmin, unsigned* __restrict__ colmin) {

    __shared__ unsigned coltile[MH];   // 2 KB
    __shared__ unsigned rowtile[XT];   // 0.5 KB

    const int b  = blockIdx.z;
    const int xt = blockIdx.x;         // 0..31
    const int mh = blockIdx.y;         // 0..7
    const int n0 = xt * XT;
    const int m0 = mh * MH;
    const int tid  = threadIdx.x;
    const int wave = tid >> 6;
    const int lane = tid & 63;
    const int lc   = lane & 15;        // A/B row, C col
    const int quad = lane >> 4;        // k-chunk, C row group
    const int wm = wave >> 1;
    const int wn = wave & 1;

    for (int c = tid; c < MH; c += 256) coltile[c] = FINF_BITS;
    if (tid < XT) rowtile[tid] = FINF_BITS;

    // ---- x fragments: registers for the whole block ----
    const ushort* Xb = X + ((size_t)b * NN + n0) * CC;
    bf16x8 xf[4][4];
#pragma unroll
    for (int i = 0; i < 4; ++i)
#pragma unroll
        for (int kt = 0; kt < 4; ++kt)
            xf[i][kt] = *(const bf16x8*)(Xb + (size_t)(wm * 64 + i * 16 + lc) * CC +
                                         kt * 32 + quad * 8);

    __syncthreads();   // rowtile/coltile init visible before LDS atomics

    const ushort* Yb  = Y + ((size_t)b * MM + m0) * CC;
    const float*  ynb = yn + (size_t)b * MM + m0;
    const float*  xnb = xn + (size_t)b * NN + n0;

#pragma unroll 1
    for (int mt = 0; mt < NMT; ++mt) {
        const ushort* Ymt = Yb + (size_t)(mt * MT + wn * 64 + lc) * CC + quad * 8;

        float ynr[4];
#pragma unroll
        for (int j = 0; j < 4; ++j)
            ynr[j] = ynb[mt * MT + wn * 64 + j * 16 + lc];

        f32x4 acc[4][4];
        const f32x4 z = {0.f, 0.f, 0.f, 0.f};
#pragma unroll
        for (int kt = 0; kt < 4; ++kt) {
            bf16x8 yf[4];
#pragma unroll
            for (int j = 0; j < 4; ++j)
                yf[j] = *(const bf16x8*)(Ymt + (size_t)j * 16 * CC + kt * 32);
#pragma unroll
            for (int j = 0; j < 4; ++j)
#pragma unroll
                for (int i = 0; i < 4; ++i)
                    acc[i][j] = __builtin_amdgcn_mfma_f32_16x16x32_bf16(
                        xf[i][kt], yf[j], (kt == 0) ? z : acc[i][j], 0, 0, 0);
        }

        // ---- epilogue: d^2 mins, one i-chunk at a time (low reg pressure) ----
        float cmv[4];
#pragma unroll
        for (int j = 0; j < 4; ++j) cmv[j] = __builtin_inff();

#pragma unroll
        for (int i = 0; i < 4; ++i) {
            float4 t = *(const float4*)(xnb + wm * 64 + i * 16 + quad * 4);
            float xnr[4] = {t.x, t.y, t.z, t.w};
            float rloc[4];
#pragma unroll
            for (int r = 0; r < 4; ++r) rloc[r] = __builtin_inff();
#pragma unroll
            for (int j = 0; j < 4; ++j) {
                f32x4 a = acc[i][j];
#pragma unroll
                for (int r = 0; r < 4; ++r) {
                    float d2 = xnr[r] + fmaf(-2.0f, a[r], ynr[j]);
                    rloc[r] = fminf(rloc[r], d2);
                    cmv[j]  = fminf(cmv[j], d2);
                }
            }
            // row reduce across the 16 lc lanes sharing these rows
#pragma unroll
            for (int mask = 1; mask <= 8; mask <<= 1)
#pragma unroll
                for (int r = 0; r < 4; ++r)
                    rloc[r] = fminf(rloc[r], __shfl_xor(rloc[r], mask, 64));
            if (lc == 0) {
#pragma unroll
                for (int r = 0; r < 4; ++r)
                    atomicMin(&rowtile[wm * 64 + i * 16 + quad * 4 + r],
                              __float_as_uint(fmaxf(rloc[r], 0.0f)));
            }
        }

        // col reduce across quads, then LDS atomic
#pragma unroll
        for (int mask = 16; mask <= 32; mask <<= 1)
#pragma unroll
            for (int j = 0; j < 4; ++j)
                cmv[j] = fminf(cmv[j], __shfl_xor(cmv[j], mask, 64));
        if (quad == 0) {
#pragma unroll
            for (int j = 0; j < 4; ++j)
                atomicMin(&coltile[mt * MT + wn * 64 + j * 16 + lc],
                          __float_as_uint(fmaxf(cmv[j], 0.0f)));
        }
    }

    // ---- flush tile minima with global atomics ----
    __syncthreads();
    if (tid < XT)
        atomicMin(&rowmin[(size_t)b * NN + n0 + tid], rowtile[tid]);
    for (int c = tid; c < MH; c += 256)
        atomicMin(&colmin[(size_t)b * MM + m0 + c], coltile[c]);
}

// ---------------------------------------------------------------------------
// finalize: total = (sum w1*sqrt(rowmin) + sum w2*sqrt(colmin)) / 2
// ---------------------------------------------------------------------------
__global__ void ch_finalize(const unsigned* __restrict__ rowmin,
                            const unsigned* __restrict__ colmin,
                            const float* __restrict__ w1,
                            const float* __restrict__ w2,
                            float* __restrict__ out) {
    int i = blockIdx.x * blockDim.x + threadIdx.x;
    int stride = gridDim.x * blockDim.x;
    float s = 0.f;
    for (int idx = i; idx < BS * NN; idx += stride)
        s += w1[idx] * sqrtf(__uint_as_float(rowmin[idx])) +
             w2[idx] * sqrtf(__uint_as_float(colmin[idx]));
#pragma unroll
    for (int off = 32; off > 0; off >>= 1) s += __shfl_down(s, off, 64);
    __shared__ float ls[4];
    int lane = threadIdx.x & 63, wv = threadIdx.x >> 6;
    if (lane == 0) ls[wv] = s;
    __syncthreads();
    if (threadIdx.x == 0) {
        float t = ls[0] + ls[1] + ls[2] + ls[3];
        atomicAdd(out, 0.5f * t);
    }
}

extern "C" void kernel_launch(void* const* d_in, const int* in_sizes, int n_in,
                              void* d_out, int out_size, void* d_ws, size_t ws_size,
                              hipStream_t stream) {
    const float* set1 = (const float*)d_in[0];
    const float* set2 = (const float*)d_in[1];
    const float* w1   = (const float*)d_in[2];
    const float* w2   = (const float*)d_in[3];
    float* out = (float*)d_out;

    // workspace layout (~16.5 MiB)
    ushort*   x16    = (ushort*)d_ws;                        // 8 MB
    ushort*   y16    = x16 + (size_t)BS * NN * CC;           // 8 MB
    float*    xn     = (float*)(y16 + (size_t)BS * MM * CC); // 128 KB
    float*    yn     = xn + BS * NN;                         // 128 KB
    unsigned* rowmin = (unsigned*)(yn + BS * MM);            // 128 KB (d^2 bits)
    unsigned* colmin = rowmin + BS * NN;                     // 128 KB (d^2 bits)

    ch_prep<<<BS * NN * CC / 4 / 256, 256, 0, stream>>>(
        set1, set2, x16, y16, xn, yn, rowmin, colmin, out);

    dim3 grid(NXT, MM / MH, BS);
    ch_tile<<<grid, 256, 0, stream>>>(x16, y16, xn, yn, rowmin, colmin);

    ch_finalize<<<64, 256, 0, stream>>>(rowmin, colmin, w1, w2, out);
}

// Round 8
// 154.943 us; speedup vs baseline: 1.7090x; 1.0878x over previous
//
#include <hip/hip_runtime.h>

// Problem constants (fixed by setup_inputs: bs=8, N=M=4096, C=128)
#define BS 8
#define NN 4096
#define MM 4096
#define CC 128
#define XT 128            // x rows per block
#define MT 128            // cols per m-tile
#define MH 2048           // cols per block
#define NMT (MH / MT)     // 16 m-tiles per block
#define NXT (NN / XT)     // 32 x-tiles

#define FINF_BITS 0x7F800000u

typedef __attribute__((ext_vector_type(8))) short bf16x8;
typedef __attribute__((ext_vector_type(4))) float f32x4;

// RNE fp32 -> bf16 (inputs are finite normals)
__device__ inline ushort f2bf(float f) {
    unsigned u = __float_as_uint(f);
    unsigned r = (u + 0x7FFFu + ((u >> 16) & 1u)) >> 16;
    return (ushort)r;
}

// ---------------------------------------------------------------------------
// prep: fp32->bf16 copies + exact fp32 row norms + rowmin/colmin=+inf + out=0
// ---------------------------------------------------------------------------
__global__ void ch_prep(const float* __restrict__ x, const float* __restrict__ y,
                        ushort* __restrict__ x16, ushort* __restrict__ y16,
                        float* __restrict__ xn, float* __restrict__ yn,
                        unsigned* __restrict__ rowmin, unsigned* __restrict__ colmin,
                        float* __restrict__ out) {
    int gid = blockIdx.x * blockDim.x + threadIdx.x;
    size_t i = (size_t)gid * 4;

    float4 v = *(const float4*)(x + i);
    ushort4 o;
    o.x = f2bf(v.x); o.y = f2bf(v.y); o.z = f2bf(v.z); o.w = f2bf(v.w);
    *(ushort4*)(x16 + i) = o;
    float sx = v.x * v.x + v.y * v.y + v.z * v.z + v.w * v.w;

    float4 w = *(const float4*)(y + i);
    ushort4 p;
    p.x = f2bf(w.x); p.y = f2bf(w.y); p.z = f2bf(w.z); p.w = f2bf(w.w);
    *(ushort4*)(y16 + i) = p;
    float sy = w.x * w.x + w.y * w.y + w.z * w.z + w.w * w.w;

#pragma unroll
    for (int mask = 1; mask <= 16; mask <<= 1) {
        sx += __shfl_xor(sx, mask, 64);
        sy += __shfl_xor(sy, mask, 64);
    }
    if ((threadIdx.x & 31) == 0) {
        int row = gid >> 5;
        xn[row] = sx;
        yn[row] = sy;
    }
    if (gid < BS * NN) {
        rowmin[gid] = FINF_BITS;
        colmin[gid] = FINF_BITS;
    }
    if (gid == 0) out[0] = 0.0f;
}

// ---------------------------------------------------------------------------
// main kernel (R8): 512-thread blocks, 8 waves = 2 row-halves x 4 col-quarters
// of a 128x128 tile -> per-wave acc is only 4x2 MFMAs (32 AGPR).
// x-tile staged once into XOR-swizzled LDS (shared by all 8 waves; kills the
// 64-reg xf array). y fragments direct from global (L2-resident). One barrier
// per block; none in the m-loop. Row d^2 mins persist in registers (16);
// col mins shuffle-reduced then LDS atomicMin; flushed once at block end.
// No launch_bounds min-waves coercion (R5/R6: coercion => scratch spill);
// target is NATURAL 3-4 waves/SIMD from the smaller footprint.
// ---------------------------------------------------------------------------
__global__ __launch_bounds__(512) void ch_tile(
    const ushort* __restrict__ X, const ushort* __restrict__ Y,
    const float* __restrict__ xn, const float* __restrict__ yn,
    unsigned* __restrict__ rowmin, unsigned* __restrict__ colmin) {

    __shared__ ushort xs[XT * CC];     // 32 KB, chunk-swizzled
    __shared__ unsigned coltile[MH];   // 8 KB
    __shared__ unsigned rowtile[XT];   // 0.5 KB

    const int b  = blockIdx.z;
    const int xt = blockIdx.x;         // 0..31
    const int mh = blockIdx.y;         // 0..1
    const int n0 = xt * XT;
    const int m0 = mh * MH;
    const int tid  = threadIdx.x;
    const int wave = tid >> 6;         // 0..7
    const int lane = tid & 63;
    const int lc   = lane & 15;        // A/B row, C col
    const int quad = lane >> 4;        // k-chunk, C row group
    const int wm = wave >> 2;          // row half (0/1)
    const int wn = wave & 3;           // col quarter (0..3)

    // ---- stage x tile into swizzled LDS (16B chunk c at slot c^(row&7)) ----
    const ushort* Xb = X + ((size_t)b * NN + n0) * CC;
#pragma unroll
    for (int s = 0; s < 4; ++s) {
        int flat = s * 512 + tid;      // 2048 chunks = 128 rows x 16
        int r = flat >> 4, c = flat & 15;
        int cs = c ^ (r & 7);
        *(bf16x8*)(xs + r * CC + cs * 8) = *(const bf16x8*)(Xb + (size_t)r * CC + c * 8);
    }
    for (int c2 = tid; c2 < MH; c2 += 512) coltile[c2] = FINF_BITS;
    if (tid < XT) rowtile[tid] = FINF_BITS;
    __syncthreads();

    float rm[4][4];
#pragma unroll
    for (int i = 0; i < 4; ++i)
#pragma unroll
        for (int r = 0; r < 4; ++r) rm[i][r] = __builtin_inff();

    const ushort* Yb  = Y + ((size_t)b * MM + m0) * CC;
    const float*  ynb = yn + (size_t)b * MM + m0;
    const float*  xnb = xn + (size_t)b * NN + n0;
    const int xrow = (wm * 64 + lc) * CC;
    const int xsw  = lc & 7;

#pragma unroll 1
    for (int mt = 0; mt < NMT; ++mt) {
        const ushort* Ymt = Yb + (size_t)(mt * MT + wn * 32 + lc) * CC + quad * 8;

        float ynr[2];
#pragma unroll
        for (int j = 0; j < 2; ++j)
            ynr[j] = ynb[mt * MT + wn * 32 + j * 16 + lc];

        f32x4 acc[4][2];
        const f32x4 z = {0.f, 0.f, 0.f, 0.f};
#pragma unroll
        for (int kt = 0; kt < 4; ++kt) {
            bf16x8 af[4], yf[2];
            const int cs = ((kt * 4 + quad) ^ xsw) * 8;
#pragma unroll
            for (int j = 0; j < 2; ++j)
                yf[j] = *(const bf16x8*)(Ymt + (size_t)j * 16 * CC + kt * 32);
#pragma unroll
            for (int i = 0; i < 4; ++i)
                af[i] = *(const bf16x8*)(xs + xrow + i * 16 * CC + cs);
#pragma unroll
            for (int j = 0; j < 2; ++j)
#pragma unroll
                for (int i = 0; i < 4; ++i)
                    acc[i][j] = __builtin_amdgcn_mfma_f32_16x16x32_bf16(
                        af[i], yf[j], (kt == 0) ? z : acc[i][j], 0, 0, 0);
        }

        // ---- epilogue: d^2 mins (sqrt/clamp deferred) ----
        float cmv[2];
#pragma unroll
        for (int j = 0; j < 2; ++j) cmv[j] = __builtin_inff();

#pragma unroll
        for (int i = 0; i < 4; ++i) {
            float4 t = *(const float4*)(xnb + wm * 64 + i * 16 + quad * 4);
            float xnr[4] = {t.x, t.y, t.z, t.w};
#pragma unroll
            for (int j = 0; j < 2; ++j) {
                f32x4 a = acc[i][j];
#pragma unroll
                for (int r = 0; r < 4; ++r) {
                    float d2 = xnr[r] + fmaf(-2.0f, a[r], ynr[j]);
                    rm[i][r] = fminf(rm[i][r], d2);
                    cmv[j]   = fminf(cmv[j], d2);
                }
            }
        }

        // col reduce across quads, then LDS atomic
#pragma unroll
        for (int mask = 16; mask <= 32; mask <<= 1)
#pragma unroll
            for (int j = 0; j < 2; ++j)
                cmv[j] = fminf(cmv[j], __shfl_xor(cmv[j], mask, 64));
        if (quad == 0) {
#pragma unroll
            for (int j = 0; j < 2; ++j)
                atomicMin(&coltile[mt * MT + wn * 32 + j * 16 + lc],
                          __float_as_uint(fmaxf(cmv[j], 0.0f)));
        }
    }

    // ---- row mins: reduce across the 16 lc lanes, LDS atomic once ----
#pragma unroll
    for (int mask = 1; mask <= 8; mask <<= 1)
#pragma unroll
        for (int i = 0; i < 4; ++i)
#pragma unroll
            for (int r = 0; r < 4; ++r)
                rm[i][r] = fminf(rm[i][r], __shfl_xor(rm[i][r], mask, 64));
    if (lc == 0) {
#pragma unroll
        for (int i = 0; i < 4; ++i)
#pragma unroll
            for (int r = 0; r < 4; ++r)
                atomicMin(&rowtile[wm * 64 + i * 16 + quad * 4 + r],
                          __float_as_uint(fmaxf(rm[i][r], 0.0f)));
    }

    // ---- flush tile minima with global atomics ----
    __syncthreads();
    if (tid < XT)
        atomicMin(&rowmin[(size_t)b * NN + n0 + tid], rowtile[tid]);
    for (int c2 = tid; c2 < MH; c2 += 512)
        atomicMin(&colmin[(size_t)b * MM + m0 + c2], coltile[c2]);
}

// ---------------------------------------------------------------------------
// finalize: total = (sum w1*sqrt(rowmin) + sum w2*sqrt(colmin)) / 2
// ---------------------------------------------------------------------------
__global__ void ch_finalize(const unsigned* __restrict__ rowmin,
                            const unsigned* __restrict__ colmin,
                            const float* __restrict__ w1,
                            const float* __restrict__ w2,
                            float* __restrict__ out) {
    int i = blockIdx.x * blockDim.x + threadIdx.x;
    int stride = gridDim.x * blockDim.x;
    float s = 0.f;
    for (int idx = i; idx < BS * NN; idx += stride)
        s += w1[idx] * sqrtf(__uint_as_float(rowmin[idx])) +
             w2[idx] * sqrtf(__uint_as_float(colmin[idx]));
#pragma unroll
    for (int off = 32; off > 0; off >>= 1) s += __shfl_down(s, off, 64);
    __shared__ float ls[4];
    int lane = threadIdx.x & 63, wv = threadIdx.x >> 6;
    if (lane == 0) ls[wv] = s;
    __syncthreads();
    if (threadIdx.x == 0) {
        float t = ls[0] + ls[1] + ls[2] + ls[3];
        atomicAdd(out, 0.5f * t);
    }
}

extern "C" void kernel_launch(void* const* d_in, const int* in_sizes, int n_in,
                              void* d_out, int out_size, void* d_ws, size_t ws_size,
                              hipStream_t stream) {
    const float* set1 = (const float*)d_in[0];
    const float* set2 = (const float*)d_in[1];
    const float* w1   = (const float*)d_in[2];
    const float* w2   = (const float*)d_in[3];
    float* out = (float*)d_out;

    // workspace layout (~16.5 MiB)
    ushort*   x16    = (ushort*)d_ws;                        // 8 MB
    ushort*   y16    = x16 + (size_t)BS * NN * CC;           // 8 MB
    float*    xn     = (float*)(y16 + (size_t)BS * MM * CC); // 128 KB
    float*    yn     = xn + BS * NN;                         // 128 KB
    unsigned* rowmin = (unsigned*)(yn + BS * MM);            // 128 KB (d^2 bits)
    unsigned* colmin = rowmin + BS * NN;                     // 128 KB (d^2 bits)

    ch_prep<<<BS * NN * CC / 4 / 256, 256, 0, stream>>>(
        set1, set2, x16, y16, xn, yn, rowmin, colmin, out);

    dim3 grid(NXT, MM / MH, BS);
    ch_tile<<<grid, 512, 0, stream>>>(x16, y16, xn, yn, rowmin, colmin);

    ch_finalize<<<64, 256, 0, stream>>>(rowmin, colmin, w1, w2, out);
}